// Round 3
// baseline (282.474 us; speedup 1.0000x reference)
//
#include <hip/hip_runtime.h>
#include <math.h>

// Problem constants (from reference): L=16384, H=256, P=512.
#define L_SEQ 16384
#define H_DIM 256
#define P_DIM 512
#define CL 64                 // scan chunk length
#define NC (L_SEQ / CL)       // 256 chunks

// params layout (SoA, stride P_DIM): 0..3 = m00,m01,m10,m11 ; 4 = dts ; 5 = dts^2 ;
// 6..9 = Mc = M^CL
__global__ void prep_params(const float* __restrict__ A_diag,
                            const float* __restrict__ G_diag,
                            const float* __restrict__ dt,
                            float* __restrict__ prm) {
  int p = blockIdx.x * blockDim.x + threadIdx.x;
  if (p >= P_DIM) return;
  float dts = 1.0f / (1.0f + expf(-dt[p]));
  float G = fmaxf(G_diag[p], 0.0f);
  float g = dts * G;
  float root = sqrtf(1.0f - g);
  float denom = fmaxf(dts * dts, 1e-6f);
  float A_low  = (2.0f - g - 2.0f * root) / denom;
  float A_high = (2.0f - g + 2.0f * root) / denom;
  float Ad = A_diag[p];
  float A = A_low + fmaxf(Ad - A_low, 0.0f) - fmaxf(Ad - A_high, 0.0f);
  float m00 = 1.0f - g;
  float m01 = -dts * A;
  float m10 = dts * (1.0f - g);
  float m11 = 1.0f - dts * dts * A;
  // Mc = M^CL, CL=64 -> 6 squarings. Spectral radius sqrt(1-g) <= 1 -> stable.
  float c00 = m00, c01 = m01, c10 = m10, c11 = m11;
#pragma unroll
  for (int i = 0; i < 6; i++) {
    float n00 = c00 * c00 + c01 * c10;
    float n01 = c00 * c01 + c01 * c11;
    float n10 = c10 * c00 + c11 * c10;
    float n11 = c10 * c01 + c11 * c11;
    c00 = n00; c01 = n01; c10 = n10; c11 = n11;
  }
  prm[0 * P_DIM + p] = m00;
  prm[1 * P_DIM + p] = m01;
  prm[2 * P_DIM + p] = m10;
  prm[3 * P_DIM + p] = m11;
  prm[4 * P_DIM + p] = dts;
  prm[5 * P_DIM + p] = dts * dts;
  prm[6 * P_DIM + p] = c00;
  prm[7 * P_DIM + p] = c01;
  prm[8 * P_DIM + p] = c10;
  prm[9 * P_DIM + p] = c11;
}

// W1[h][2p+c] = B[p][h][c]  -> shape (H_DIM, 2*P_DIM) row-major
__global__ void prep_w1(const float* __restrict__ B, float* __restrict__ W1) {
  int idx = blockIdx.x * blockDim.x + threadIdx.x;
  if (idx >= H_DIM * 2 * P_DIM) return;
  int h = idx >> 10;          // / (2*P_DIM) = /1024
  int pc = idx & 1023;
  int p = pc >> 1, c = pc & 1;
  W1[idx] = B[(p * H_DIM + h) * 2 + c];
}

// W2[2p+c][h] = (c==0 ? C[h][p][0] : -C[h][p][1]) -> shape (2*P_DIM, H_DIM)
__global__ void prep_w2(const float* __restrict__ C, float* __restrict__ W2) {
  int idx = blockIdx.x * blockDim.x + threadIdx.x;
  if (idx >= 2 * P_DIM * H_DIM) return;
  int row = idx >> 8;         // / H_DIM
  int h = idx & 255;
  int p = row >> 1, c = row & 1;
  float v = C[(h * P_DIM + p) * 2 + c];
  W2[idx] = c ? -v : v;
}

// Plain fp32 GEMM: Out[M x N] = A[M x K] @ W[K x N]; 64x64 tile, 256 threads,
// 4x4 micro-tile. EPI: Out += U * Dv[col] (elementwise row x diag).
template <bool EPI>
__global__ __launch_bounds__(256) void gemm_f32(
    const float* __restrict__ A, const float* __restrict__ W,
    float* __restrict__ Out, int M, int N, int K,
    const float* __restrict__ U, const float* __restrict__ Dv) {
  __shared__ float As[16][68];  // As[k][row], padded (+4) to break bank conflicts
  __shared__ float Ws[16][64];  // Ws[k][col]
  const int bm = blockIdx.x * 64;
  const int bn = blockIdx.y * 64;
  const int tid = threadIdx.x;
  const int tx = tid & 15;
  const int ty = tid >> 4;
  const int ar = tid >> 2;          // 0..63
  const int ak = (tid & 3) << 2;    // 0,4,8,12
  const int wk = tid >> 4;          // 0..15
  const int wc = (tid & 15) << 2;   // 0..60

  float acc[4][4] = {{0.f}};

  for (int k0 = 0; k0 < K; k0 += 16) {
    float4 av = *(const float4*)(A + (size_t)(bm + ar) * K + k0 + ak);
    float4 wv = *(const float4*)(W + (size_t)(k0 + wk) * N + bn + wc);
    __syncthreads();
    As[ak + 0][ar] = av.x;
    As[ak + 1][ar] = av.y;
    As[ak + 2][ar] = av.z;
    As[ak + 3][ar] = av.w;
    *(float4*)&Ws[wk][wc] = wv;
    __syncthreads();
#pragma unroll
    for (int kk = 0; kk < 16; kk++) {
      float4 a4 = *(const float4*)&As[kk][ty << 2];
      float4 w4 = *(const float4*)&Ws[kk][tx << 2];
      float aa[4] = {a4.x, a4.y, a4.z, a4.w};
      float ww[4] = {w4.x, w4.y, w4.z, w4.w};
#pragma unroll
      for (int i = 0; i < 4; i++)
#pragma unroll
        for (int j = 0; j < 4; j++)
          acc[i][j] = fmaf(aa[i], ww[j], acc[i][j]);
    }
  }

  const int col0 = bn + (tx << 2);
#pragma unroll
  for (int i = 0; i < 4; i++) {
    int row = bm + (ty << 2) + i;
    float4 o = make_float4(acc[i][0], acc[i][1], acc[i][2], acc[i][3]);
    if (EPI) {
      float4 uu = *(const float4*)(U + (size_t)row * N + col0);
      float4 dd = *(const float4*)(Dv + col0);
      o.x = fmaf(uu.x, dd.x, o.x);
      o.y = fmaf(uu.y, dd.y, o.y);
      o.z = fmaf(uu.z, dd.z, o.z);
      o.w = fmaf(uu.w, dd.w, o.w);
    }
    *(float4*)(Out + (size_t)row * N + col0) = o;
  }
}

// Phase A: per (chunk c, state p) local scan from zero state over CL steps.
// Bu is [L][P] float2 (re, im). finals[c*P+p] = (x1r, x2r, x1i, x2i).
__global__ __launch_bounds__(256) void scan_local(
    const float2* __restrict__ Bu, const float* __restrict__ prm,
    float4* __restrict__ finals) {
  int tid = blockIdx.x * 256 + threadIdx.x;
  int p = tid & (P_DIM - 1);
  int c = tid >> 9;
  float m00 = prm[0 * P_DIM + p], m01 = prm[1 * P_DIM + p];
  float m10 = prm[2 * P_DIM + p], m11 = prm[3 * P_DIM + p];
  float dts = prm[4 * P_DIM + p], dts2 = prm[5 * P_DIM + p];
  float x1r = 0.f, x2r = 0.f, x1i = 0.f, x2i = 0.f;
  const float2* src = Bu + (size_t)c * CL * P_DIM + p;
#pragma unroll 8
  for (int i = 0; i < CL; i++) {
    float2 bu = src[(size_t)i * P_DIM];
    float n1r = fmaf(m00, x1r, fmaf(m01, x2r, dts * bu.x));
    float n2r = fmaf(m10, x1r, fmaf(m11, x2r, dts2 * bu.x));
    float n1i = fmaf(m00, x1i, fmaf(m01, x2i, dts * bu.y));
    float n2i = fmaf(m10, x1i, fmaf(m11, x2i, dts2 * bu.y));
    x1r = n1r; x2r = n2r; x1i = n1i; x2i = n2i;
  }
  finals[c * P_DIM + p] = make_float4(x1r, x2r, x1i, x2i);
}

// Phase B: Hillis-Steele log-scan over the NC chunks, one block per p.
// Element matrices are all Mc (time-invariant), so the step matrix just squares.
// carry[c*P+p] = exclusive scan = state entering chunk c.
__global__ __launch_bounds__(NC) void scan_carry(
    const float4* __restrict__ finals, const float* __restrict__ prm,
    float4* __restrict__ carry) {
  int p = blockIdx.x;
  int c = threadIdx.x;  // 0..NC-1
  __shared__ float4 sb[NC];
  float m00 = prm[6 * P_DIM + p], m01 = prm[7 * P_DIM + p];
  float m10 = prm[8 * P_DIM + p], m11 = prm[9 * P_DIM + p];
  float4 b = finals[c * P_DIM + p];
  for (int o = 1; o < NC; o <<= 1) {
    sb[c] = b;
    __syncthreads();
    float4 nb = (c >= o) ? sb[c - o] : make_float4(0.f, 0.f, 0.f, 0.f);
    __syncthreads();
    b.x = fmaf(m00, nb.x, fmaf(m01, nb.y, b.x));
    b.y = fmaf(m10, nb.x, fmaf(m11, nb.y, b.y));
    b.z = fmaf(m00, nb.z, fmaf(m01, nb.w, b.z));
    b.w = fmaf(m10, nb.z, fmaf(m11, nb.w, b.w));
    float n00 = m00 * m00 + m01 * m10;
    float n01 = m00 * m01 + m01 * m11;
    float n10 = m10 * m00 + m11 * m10;
    float n11 = m10 * m01 + m11 * m11;
    m00 = n00; m01 = n01; m10 = n10; m11 = n11;
  }
  if (c + 1 < NC) carry[(c + 1) * P_DIM + p] = b;
  if (c == 0) carry[p] = make_float4(0.f, 0.f, 0.f, 0.f);
}

// Phase C: redo local scan with carry-in; overwrite Bu[t][p] with ys = x2 (re,im).
__global__ __launch_bounds__(256) void scan_final(
    float2* __restrict__ Bu, const float* __restrict__ prm,
    const float4* __restrict__ carry) {
  int tid = blockIdx.x * 256 + threadIdx.x;
  int p = tid & (P_DIM - 1);
  int c = tid >> 9;
  float m00 = prm[0 * P_DIM + p], m01 = prm[1 * P_DIM + p];
  float m10 = prm[2 * P_DIM + p], m11 = prm[3 * P_DIM + p];
  float dts = prm[4 * P_DIM + p], dts2 = prm[5 * P_DIM + p];
  float4 s = carry[c * P_DIM + p];
  float x1r = s.x, x2r = s.y, x1i = s.z, x2i = s.w;
  float2* src = Bu + (size_t)c * CL * P_DIM + p;
#pragma unroll 8
  for (int i = 0; i < CL; i++) {
    float2 bu = src[(size_t)i * P_DIM];
    float n1r = fmaf(m00, x1r, fmaf(m01, x2r, dts * bu.x));
    float n2r = fmaf(m10, x1r, fmaf(m11, x2r, dts2 * bu.x));
    float n1i = fmaf(m00, x1i, fmaf(m01, x2i, dts * bu.y));
    float n2i = fmaf(m10, x1i, fmaf(m11, x2i, dts2 * bu.y));
    src[(size_t)i * P_DIM] = make_float2(n2r, n2i);  // ys = x2
    x1r = n1r; x2r = n2r; x1i = n1i; x2i = n2i;
  }
}

extern "C" void kernel_launch(void* const* d_in, const int* in_sizes, int n_in,
                              void* d_out, int out_size, void* d_ws, size_t ws_size,
                              hipStream_t stream) {
  const float* u      = (const float*)d_in[0];  // (L, H)
  const float* A_diag = (const float*)d_in[1];  // (P,)
  const float* G_diag = (const float*)d_in[2];  // (P,)
  const float* dt     = (const float*)d_in[3];  // (P,)
  const float* B      = (const float*)d_in[4];  // (P, H, 2)
  const float* C      = (const float*)d_in[5];  // (H, P, 2)
  const float* D      = (const float*)d_in[6];  // (H,)
  float* out = (float*)d_out;

  // Workspace layout (floats). Total ~74.5 MB.
  float* ws = (float*)d_ws;
  float* Y      = ws;                                   // L * 2P  (Bu, then ys in-place)
  float* W1     = Y + (size_t)L_SEQ * 2 * P_DIM;        // H * 2P
  float* W2     = W1 + (size_t)H_DIM * 2 * P_DIM;       // 2P * H
  float* prm    = W2 + (size_t)2 * P_DIM * H_DIM;       // 10 * P (pad 8192)
  float* finals = prm + 8192;                           // NC * P * 4
  float* carryb = finals + (size_t)NC * P_DIM * 4;      // NC * P * 4

  prep_params<<<(P_DIM + 255) / 256, 256, 0, stream>>>(A_diag, G_diag, dt, prm);
  prep_w1<<<(H_DIM * 2 * P_DIM + 255) / 256, 256, 0, stream>>>(B, W1);
  prep_w2<<<(2 * P_DIM * H_DIM + 255) / 256, 256, 0, stream>>>(C, W2);

  // GEMM1: Bu[L][2P] = u[L][H] @ W1[H][2P]
  gemm_f32<false><<<dim3(L_SEQ / 64, (2 * P_DIM) / 64), 256, 0, stream>>>(
      u, W1, Y, L_SEQ, 2 * P_DIM, H_DIM, nullptr, nullptr);

  // Chunked scan over time
  scan_local<<<(NC * P_DIM) / 256, 256, 0, stream>>>(
      (const float2*)Y, prm, (float4*)finals);
  scan_carry<<<P_DIM, NC, 0, stream>>>(
      (const float4*)finals, prm, (float4*)carryb);
  scan_final<<<(NC * P_DIM) / 256, 256, 0, stream>>>(
      (float2*)Y, prm, (const float4*)carryb);

  // GEMM2: out[L][H] = Y[L][2P] @ W2[2P][H] + u * D
  gemm_f32<true><<<dim3(L_SEQ / 64, H_DIM / 64), 256, 0, stream>>>(
      Y, W2, out, L_SEQ, H_DIM, 2 * P_DIM, u, D);
}

// Round 6
// 85.834 us; speedup vs baseline: 3.2910x; 3.2910x over previous
//
#include <hip/hip_runtime.h>
#include <math.h>

// Problem constants: L=16384, H=256, P=512.
#define L_SEQ 16384
#define H_DIM 256
#define P_DIM 512
#define CL 64                 // scan chunk length
#define NC (L_SEQ / CL)       // 256 chunks

typedef __attribute__((ext_vector_type(8))) short bf16x8;   // MFMA A/B fragment (4 VGPR)
typedef __attribute__((ext_vector_type(4))) float f32x4;    // MFMA C/D fragment

// RNE float -> bf16 bits
static __device__ __forceinline__ unsigned short f2bf(float f) {
  unsigned int u = __builtin_bit_cast(unsigned int, f);
  u += 0x7FFFu + ((u >> 16) & 1u);
  return (unsigned short)(u >> 16);
}
// packed (im<<16)|re bf16 pair -> floats
static __device__ __forceinline__ float bflo(unsigned int v) {
  return __builtin_bit_cast(float, v << 16);
}
static __device__ __forceinline__ float bfhi(unsigned int v) {
  return __builtin_bit_cast(float, v & 0xFFFF0000u);
}

// params layout (SoA, stride P_DIM): 0..3 = m00,m01,m10,m11 ; 4 = dts ; 5 = dts^2 ;
// 6..9 = Mc = M^CL
__global__ void prep_params(const float* __restrict__ A_diag,
                            const float* __restrict__ G_diag,
                            const float* __restrict__ dt,
                            float* __restrict__ prm) {
  int p = blockIdx.x * blockDim.x + threadIdx.x;
  if (p >= P_DIM) return;
  float dts = 1.0f / (1.0f + expf(-dt[p]));
  float G = fmaxf(G_diag[p], 0.0f);
  float g = dts * G;
  float root = sqrtf(1.0f - g);
  float denom = fmaxf(dts * dts, 1e-6f);
  float A_low  = (2.0f - g - 2.0f * root) / denom;
  float A_high = (2.0f - g + 2.0f * root) / denom;
  float Ad = A_diag[p];
  float A = A_low + fmaxf(Ad - A_low, 0.0f) - fmaxf(Ad - A_high, 0.0f);
  float m00 = 1.0f - g;
  float m01 = -dts * A;
  float m10 = dts * (1.0f - g);
  float m11 = 1.0f - dts * dts * A;
  float c00 = m00, c01 = m01, c10 = m10, c11 = m11;
#pragma unroll
  for (int i = 0; i < 6; i++) {   // M^64 by squaring; rho(M)<=1 by construction
    float n00 = c00 * c00 + c01 * c10;
    float n01 = c00 * c01 + c01 * c11;
    float n10 = c10 * c00 + c11 * c10;
    float n11 = c10 * c01 + c11 * c11;
    c00 = n00; c01 = n01; c10 = n10; c11 = n11;
  }
  prm[0 * P_DIM + p] = m00;
  prm[1 * P_DIM + p] = m01;
  prm[2 * P_DIM + p] = m10;
  prm[3 * P_DIM + p] = m11;
  prm[4 * P_DIM + p] = dts;
  prm[5 * P_DIM + p] = dts * dts;
  prm[6 * P_DIM + p] = c00;
  prm[7 * P_DIM + p] = c01;
  prm[8 * P_DIM + p] = c10;
  prm[9 * P_DIM + p] = c11;
}

// W1b[n][k] bf16, n=2p+c in [0,1024), k=h in [0,256): W1b = B^T interleaved (transposed for MFMA B-frag)
__global__ void prep_w1b(const float* __restrict__ B, unsigned short* __restrict__ W1b) {
  int idx = blockIdx.x * blockDim.x + threadIdx.x;
  if (idx >= 1024 * H_DIM) return;
  int n = idx >> 8;           // / 256
  int k = idx & 255;
  int p = n >> 1, c = n & 1;
  W1b[idx] = f2bf(B[(p * H_DIM + k) * 2 + c]);
}

// W2b[n][k] bf16, n=h in [0,256), k=2p+c in [0,1024): re -> +C_re, im -> -C_im
__global__ void prep_w2b(const float* __restrict__ C, unsigned short* __restrict__ W2b) {
  int idx = blockIdx.x * blockDim.x + threadIdx.x;
  if (idx >= H_DIM * 1024) return;
  int h = idx >> 10;
  int k = idx & 1023;
  int p = k >> 1, c = k & 1;
  float v = C[(h * P_DIM + p) * 2 + c];
  W2b[idx] = f2bf(c ? -v : v);
}

// u fp32 -> bf16 plane (vectorized x4)
__global__ void cast_u(const float* __restrict__ u, unsigned short* __restrict__ ub) {
  int i = blockIdx.x * blockDim.x + threadIdx.x;
  if (i >= (L_SEQ * H_DIM) / 4) return;
  float4 v = ((const float4*)u)[i];
  ushort4 o;
  o.x = f2bf(v.x); o.y = f2bf(v.y); o.z = f2bf(v.z); o.w = f2bf(v.w);
  ((ushort4*)ub)[i] = o;
}

// bf16 MFMA GEMM, m97 structure: 128 x BN tile, 256 threads = 4 waves (2x2),
// BK=32, A[M][K] bf16 row-major, W[N][K] bf16 row-major (pre-transposed), fp32 acc.
// OUT_BF16: store bf16; else fp32 (+ optional EPI: out += U*Dv[col]).
template <int BN, bool OUT_BF16, bool EPI>
__global__ __launch_bounds__(256) void gemm_mfma(
    const unsigned short* __restrict__ A, const unsigned short* __restrict__ W,
    void* __restrict__ OutV, int M, int N, int K,
    const float* __restrict__ U, const float* __restrict__ Dv) {
  constexpr int WN = BN / 2;      // wave sub-tile cols
  constexpr int NF = WN / 16;     // col fragments per wave
  __shared__ unsigned short tA[128 * 32];   // [row][k] 64B rows, linear (gload_lds dest)
  __shared__ unsigned short tW[BN * 32];
  const int tid = threadIdx.x;
  const int lane = tid & 63;
  const int wid = tid >> 6;
  const int wr = wid >> 1;        // wave row (0..1), 64 rows each
  const int wc = wid & 1;         // wave col (0..1), WN cols each
  const int bm = blockIdx.x * 128;
  const int bn = blockIdx.y * BN;

  f32x4 acc[4][NF] = {};

  const int srow = lane >> 2;       // staging: row within 16-row chunk
  const int soff = (lane & 3) * 8;  // staging: k-offset (shorts), 16B per lane

  for (int k0 = 0; k0 < K; k0 += 32) {
    __syncthreads();
    // stage A tile: 128x32 bf16 = 8KB = 8 chunks of 1KB (16 rows x 64B), wave-uniform LDS base
#pragma unroll
    for (int c = wid; c < 128 / 16; c += 4) {
      const unsigned short* src = A + (size_t)(bm + c * 16 + srow) * K + k0 + soff;
      __builtin_amdgcn_global_load_lds(
          (const __attribute__((address_space(1))) void*)src,
          (__attribute__((address_space(3))) void*)(tA + c * 512), 16, 0, 0);
    }
#pragma unroll
    for (int c = wid; c < BN / 16; c += 4) {
      const unsigned short* src = W + (size_t)(bn + c * 16 + srow) * K + k0 + soff;
      __builtin_amdgcn_global_load_lds(
          (const __attribute__((address_space(1))) void*)src,
          (__attribute__((address_space(3))) void*)(tW + c * 512), 16, 0, 0);
    }
    __syncthreads();   // compiler drains vmcnt before s_barrier

    // fragments: lane l holds row (l&15), k-chunk (l>>4)*8 (contiguous bf16x8)
    const int rA = lane & 15;
    const int kc = (lane >> 4) * 8;
    bf16x8 af[4], wf[NF];
#pragma unroll
    for (int i = 0; i < 4; i++)
      af[i] = *(const bf16x8*)&tA[(wr * 64 + i * 16 + rA) * 32 + kc];
#pragma unroll
    for (int j = 0; j < NF; j++)
      wf[j] = *(const bf16x8*)&tW[(wc * WN + j * 16 + rA) * 32 + kc];
#pragma unroll
    for (int i = 0; i < 4; i++)
#pragma unroll
      for (int j = 0; j < NF; j++)
        acc[i][j] = __builtin_amdgcn_mfma_f32_16x16x32_bf16(af[i], wf[j], acc[i][j], 0, 0, 0);
  }

  // C/D layout: col = lane&15, row = (lane>>4)*4 + reg  [m89-verified]
  const int cr = (lane >> 4) * 4;
  const int cc = lane & 15;
#pragma unroll
  for (int i = 0; i < 4; i++) {
#pragma unroll
    for (int j = 0; j < NF; j++) {
      const int row0 = bm + wr * 64 + i * 16 + cr;
      const int col = bn + wc * WN + j * 16 + cc;
#pragma unroll
      for (int q = 0; q < 4; q++) {
        float v = acc[i][j][q];
        size_t idx = (size_t)(row0 + q) * N + col;
        if (OUT_BF16) {
          ((unsigned short*)OutV)[idx] = f2bf(v);
        } else {
          if (EPI) v = fmaf(U[idx], Dv[col], v);
          ((float*)OutV)[idx] = v;
        }
      }
    }
  }
}

// Phase A: local scan over CL steps from zero state. Bu16: [L][512] uints,
// each uint = packed bf16 (im<<16)|re for state p. fp32 recurrence.
__global__ __launch_bounds__(256) void scan_local(
    const unsigned int* __restrict__ Bu16, const float* __restrict__ prm,
    float4* __restrict__ finals) {
  int tid = blockIdx.x * 256 + threadIdx.x;
  int p = tid & (P_DIM - 1);
  int c = tid >> 9;
  float m00 = prm[0 * P_DIM + p], m01 = prm[1 * P_DIM + p];
  float m10 = prm[2 * P_DIM + p], m11 = prm[3 * P_DIM + p];
  float dts = prm[4 * P_DIM + p], dts2 = prm[5 * P_DIM + p];
  float x1r = 0.f, x2r = 0.f, x1i = 0.f, x2i = 0.f;
  const unsigned int* src = Bu16 + (size_t)c * CL * P_DIM + p;
#pragma unroll 8
  for (int i = 0; i < CL; i++) {
    unsigned int v = src[(size_t)i * P_DIM];
    float bx = bflo(v), by = bfhi(v);
    float n1r = fmaf(m00, x1r, fmaf(m01, x2r, dts * bx));
    float n2r = fmaf(m10, x1r, fmaf(m11, x2r, dts2 * bx));
    float n1i = fmaf(m00, x1i, fmaf(m01, x2i, dts * by));
    float n2i = fmaf(m10, x1i, fmaf(m11, x2i, dts2 * by));
    x1r = n1r; x2r = n2r; x1i = n1i; x2i = n2i;
  }
  finals[c * P_DIM + p] = make_float4(x1r, x2r, x1i, x2i);
}

// Phase B: Hillis-Steele log-scan over chunks; step matrix squares each round.
__global__ __launch_bounds__(NC) void scan_carry(
    const float4* __restrict__ finals, const float* __restrict__ prm,
    float4* __restrict__ carry) {
  int p = blockIdx.x;
  int c = threadIdx.x;
  __shared__ float4 sb[NC];
  float m00 = prm[6 * P_DIM + p], m01 = prm[7 * P_DIM + p];
  float m10 = prm[8 * P_DIM + p], m11 = prm[9 * P_DIM + p];
  float4 b = finals[c * P_DIM + p];
  for (int o = 1; o < NC; o <<= 1) {
    sb[c] = b;
    __syncthreads();
    float4 nb = (c >= o) ? sb[c - o] : make_float4(0.f, 0.f, 0.f, 0.f);
    __syncthreads();
    b.x = fmaf(m00, nb.x, fmaf(m01, nb.y, b.x));
    b.y = fmaf(m10, nb.x, fmaf(m11, nb.y, b.y));
    b.z = fmaf(m00, nb.z, fmaf(m01, nb.w, b.z));
    b.w = fmaf(m10, nb.z, fmaf(m11, nb.w, b.w));
    float n00 = m00 * m00 + m01 * m10;
    float n01 = m00 * m01 + m01 * m11;
    float n10 = m10 * m00 + m11 * m10;
    float n11 = m10 * m01 + m11 * m11;
    m00 = n00; m01 = n01; m10 = n10; m11 = n11;
  }
  if (c + 1 < NC) carry[(c + 1) * P_DIM + p] = b;
  if (c == 0) carry[p] = make_float4(0.f, 0.f, 0.f, 0.f);
}

// Phase C: redo local scan with carry-in; overwrite Bu16[t][p] with ys=x2 (bf16 pair).
// In-place safe: thread (c,p) reads then writes only its own elements.
__global__ __launch_bounds__(256) void scan_final(
    unsigned int* __restrict__ Bu16, const float* __restrict__ prm,
    const float4* __restrict__ carry) {
  int tid = blockIdx.x * 256 + threadIdx.x;
  int p = tid & (P_DIM - 1);
  int c = tid >> 9;
  float m00 = prm[0 * P_DIM + p], m01 = prm[1 * P_DIM + p];
  float m10 = prm[2 * P_DIM + p], m11 = prm[3 * P_DIM + p];
  float dts = prm[4 * P_DIM + p], dts2 = prm[5 * P_DIM + p];
  float4 s = carry[c * P_DIM + p];
  float x1r = s.x, x2r = s.y, x1i = s.z, x2i = s.w;
  unsigned int* src = Bu16 + (size_t)c * CL * P_DIM + p;
#pragma unroll 8
  for (int i = 0; i < CL; i++) {
    unsigned int v = src[(size_t)i * P_DIM];
    float bx = bflo(v), by = bfhi(v);
    float n1r = fmaf(m00, x1r, fmaf(m01, x2r, dts * bx));
    float n2r = fmaf(m10, x1r, fmaf(m11, x2r, dts2 * bx));
    float n1i = fmaf(m00, x1i, fmaf(m01, x2i, dts * by));
    float n2i = fmaf(m10, x1i, fmaf(m11, x2i, dts2 * by));
    src[(size_t)i * P_DIM] = (unsigned int)f2bf(n2r) | ((unsigned int)f2bf(n2i) << 16);
    x1r = n1r; x2r = n2r; x1i = n1i; x2i = n2i;
  }
}

extern "C" void kernel_launch(void* const* d_in, const int* in_sizes, int n_in,
                              void* d_out, int out_size, void* d_ws, size_t ws_size,
                              hipStream_t stream) {
  const float* u      = (const float*)d_in[0];  // (L, H)
  const float* A_diag = (const float*)d_in[1];
  const float* G_diag = (const float*)d_in[2];
  const float* dt     = (const float*)d_in[3];
  const float* B      = (const float*)d_in[4];  // (P, H, 2)
  const float* C      = (const float*)d_in[5];  // (H, P, 2)
  const float* D      = (const float*)d_in[6];  // (H,)
  float* out = (float*)d_out;

  // Workspace (bytes): Bu16 33.55MB | ub 8.39MB | W1b 0.5MB | W2b 0.5MB | prm | finals 2MB | carry 2MB  (~47MB)
  char* w = (char*)d_ws;
  unsigned short* Bu16 = (unsigned short*)w;                               // L*1024 bf16
  unsigned short* ub   = (unsigned short*)(w + (size_t)L_SEQ * 1024 * 2);  // L*256 bf16
  unsigned short* W1b  = ub + (size_t)L_SEQ * H_DIM;                       // 1024*256
  unsigned short* W2b  = W1b + 1024 * H_DIM;                               // 256*1024
  float* prm    = (float*)(W2b + H_DIM * 1024);                            // 10*512 (pad 8192)
  float* finals = prm + 8192;                                              // NC*P*4
  float* carryb = finals + (size_t)NC * P_DIM * 4;                         // NC*P*4

  prep_params<<<(P_DIM + 255) / 256, 256, 0, stream>>>(A_diag, G_diag, dt, prm);
  prep_w1b<<<(1024 * H_DIM) / 256, 256, 0, stream>>>(B, W1b);
  prep_w2b<<<(H_DIM * 1024) / 256, 256, 0, stream>>>(C, W2b);
  cast_u<<<(L_SEQ * H_DIM / 4 + 255) / 256, 256, 0, stream>>>(u, ub);

  // GEMM1: Bu16[L][1024] = ub[L][256] @ W1b^T  (bf16 out)
  gemm_mfma<128, true, false><<<dim3(L_SEQ / 128, 1024 / 128), 256, 0, stream>>>(
      ub, W1b, Bu16, L_SEQ, 1024, H_DIM, nullptr, nullptr);

  scan_local<<<(NC * P_DIM) / 256, 256, 0, stream>>>(
      (const unsigned int*)Bu16, prm, (float4*)finals);
  scan_carry<<<P_DIM, NC, 0, stream>>>(
      (const float4*)finals, prm, (float4*)carryb);
  scan_final<<<(NC * P_DIM) / 256, 256, 0, stream>>>(
      (unsigned int*)Bu16, prm, (const float4*)carryb);

  // GEMM2: out[L][256] = ys[L][1024] @ W2b^T + u*D  (BN=64 -> 512 blocks, 2/CU)
  gemm_mfma<64, false, true><<<dim3(L_SEQ / 128, H_DIM / 64), 256, 0, stream>>>(
      Bu16, W2b, out, L_SEQ, H_DIM, 1024, u, D);
}

// Round 7
// 83.495 us; speedup vs baseline: 3.3831x; 1.0280x over previous
//
#include <hip/hip_runtime.h>
#include <math.h>

// Problem constants: L=16384, H=256, P=512.
#define L_SEQ 16384
#define H_DIM 256
#define P_DIM 512
#define CL 64                 // scan chunk length
#define NC (L_SEQ / CL)       // 256 chunks

typedef __attribute__((ext_vector_type(8))) short bf16x8;   // MFMA A/B fragment (4 VGPR)
typedef __attribute__((ext_vector_type(4))) float f32x4;    // MFMA C/D fragment

// RNE float -> bf16 bits
static __device__ __forceinline__ unsigned short f2bf(float f) {
  unsigned int u = __builtin_bit_cast(unsigned int, f);
  u += 0x7FFFu + ((u >> 16) & 1u);
  return (unsigned short)(u >> 16);
}
// packed (im<<16)|re bf16 pair -> floats
static __device__ __forceinline__ float bflo(unsigned int v) {
  return __builtin_bit_cast(float, v << 16);
}
static __device__ __forceinline__ float bfhi(unsigned int v) {
  return __builtin_bit_cast(float, v & 0xFFFF0000u);
}

// One merged prep dispatch (branch by blockIdx: wave-uniform, no divergence):
//   blocks [0,2):       prep_params -> prm  (10 x P_DIM SoA; [0..3]=M, [4]=dts, [5]=dts^2, [6..9]=M^CL)
//   blocks [2,1026):    W1b[n][k] = bf16(B[p][h][c]), n=2p+c, k=h       (1024 x 256)
//   blocks [1026,2050): W2b[n][k] = bf16(+/-C[h][p][c]), n=h, k=2p+c    (256 x 1024)
//   blocks [2050,6146): cast u fp32 -> ub bf16 (float4 -> ushort4)
__global__ __launch_bounds__(256) void prep_all(
    const float* __restrict__ A_diag, const float* __restrict__ G_diag,
    const float* __restrict__ dt, const float* __restrict__ B,
    const float* __restrict__ C, const float* __restrict__ u,
    float* __restrict__ prm, unsigned short* __restrict__ W1b,
    unsigned short* __restrict__ W2b, unsigned short* __restrict__ ub) {
  const int b = blockIdx.x;
  const int t = threadIdx.x;
  if (b < 2) {
    int p = b * 256 + t;
    float dts = 1.0f / (1.0f + expf(-dt[p]));
    float G = fmaxf(G_diag[p], 0.0f);
    float g = dts * G;
    float root = sqrtf(1.0f - g);
    float denom = fmaxf(dts * dts, 1e-6f);
    float A_low  = (2.0f - g - 2.0f * root) / denom;
    float A_high = (2.0f - g + 2.0f * root) / denom;
    float Ad = A_diag[p];
    float A = A_low + fmaxf(Ad - A_low, 0.0f) - fmaxf(Ad - A_high, 0.0f);
    float m00 = 1.0f - g;
    float m01 = -dts * A;
    float m10 = dts * (1.0f - g);
    float m11 = 1.0f - dts * dts * A;
    float c00 = m00, c01 = m01, c10 = m10, c11 = m11;
#pragma unroll
    for (int i = 0; i < 6; i++) {   // M^64 by squaring; rho(M)<=1 by construction
      float n00 = c00 * c00 + c01 * c10;
      float n01 = c00 * c01 + c01 * c11;
      float n10 = c10 * c00 + c11 * c10;
      float n11 = c10 * c01 + c11 * c11;
      c00 = n00; c01 = n01; c10 = n10; c11 = n11;
    }
    prm[0 * P_DIM + p] = m00;
    prm[1 * P_DIM + p] = m01;
    prm[2 * P_DIM + p] = m10;
    prm[3 * P_DIM + p] = m11;
    prm[4 * P_DIM + p] = dts;
    prm[5 * P_DIM + p] = dts * dts;
    prm[6 * P_DIM + p] = c00;
    prm[7 * P_DIM + p] = c01;
    prm[8 * P_DIM + p] = c10;
    prm[9 * P_DIM + p] = c11;
  } else if (b < 2 + 1024) {
    int idx = (b - 2) * 256 + t;          // < 1024*256
    int n = idx >> 8;
    int k = idx & 255;
    int p = n >> 1, c = n & 1;
    W1b[idx] = f2bf(B[(p * H_DIM + k) * 2 + c]);
  } else if (b < 2 + 2048) {
    int idx = (b - 1026) * 256 + t;       // < 256*1024
    int h = idx >> 10;
    int k = idx & 1023;
    int p = k >> 1, c = k & 1;
    float v = C[(h * P_DIM + p) * 2 + c];
    W2b[idx] = f2bf(c ? -v : v);
  } else {
    int idx = (b - 2050) * 256 + t;       // < L*H/4
    float4 v = ((const float4*)u)[idx];
    ushort4 o;
    o.x = f2bf(v.x); o.y = f2bf(v.y); o.z = f2bf(v.z); o.w = f2bf(v.w);
    ((ushort4*)ub)[idx] = o;
  }
}

// bf16 MFMA GEMM (m97 structure), generalized tile: BM x BN, 256 threads = 4 waves (2x2),
// BK=32. A[M][K] bf16 row-major, W[N][K] bf16 row-major (pre-transposed), fp32 acc.
// OUT_BF16: store bf16; else fp32 (+ optional EPI: out += U*Dv[col]).
// GEMM1: BM=128,BN=128 grid(128,8).  GEMM2: BM=32,BN=256 grid(512,1) -> ys read ONCE,
// W2b (0.5MB) is the re-read operand (L2-resident per XCD); 2 blocks/CU for barrier overlap.
template <int BM, int BN, bool OUT_BF16, bool EPI>
__global__ __launch_bounds__(256) void gemm_mfma(
    const unsigned short* __restrict__ A, const unsigned short* __restrict__ W,
    void* __restrict__ OutV, int M, int N, int K,
    const float* __restrict__ U, const float* __restrict__ Dv) {
  constexpr int WR = BM / 2;      // wave rows
  constexpr int MR = WR / 16;     // row fragments per wave
  constexpr int WC = BN / 2;      // wave cols
  constexpr int NF = WC / 16;     // col fragments per wave
  __shared__ unsigned short tA[BM * 32];   // [row][k], 64B rows, linear (gload_lds dest)
  __shared__ unsigned short tW[BN * 32];
  const int tid = threadIdx.x;
  const int lane = tid & 63;
  const int wid = tid >> 6;
  const int wr = wid >> 1;        // wave row (0..1)
  const int wc = wid & 1;         // wave col (0..1)
  const int bm = blockIdx.x * BM;
  const int bn = blockIdx.y * BN;

  f32x4 acc[MR][NF] = {};

  const int srow = lane >> 2;       // staging: row within 16-row chunk
  const int soff = (lane & 3) * 8;  // staging: k-offset (shorts), 16B per lane

  for (int k0 = 0; k0 < K; k0 += 32) {
    __syncthreads();
    // stage tiles as 1KB chunks (16 rows x 64B), wave-uniform LDS base + lane*16B
#pragma unroll
    for (int c = wid; c < BM / 16; c += 4) {
      const unsigned short* src = A + (size_t)(bm + c * 16 + srow) * K + k0 + soff;
      __builtin_amdgcn_global_load_lds(
          (const __attribute__((address_space(1))) void*)src,
          (__attribute__((address_space(3))) void*)(tA + c * 512), 16, 0, 0);
    }
#pragma unroll
    for (int c = wid; c < BN / 16; c += 4) {
      const unsigned short* src = W + (size_t)(bn + c * 16 + srow) * K + k0 + soff;
      __builtin_amdgcn_global_load_lds(
          (const __attribute__((address_space(1))) void*)src,
          (__attribute__((address_space(3))) void*)(tW + c * 512), 16, 0, 0);
    }
    __syncthreads();   // compiler drains vmcnt before s_barrier

    // fragments: lane l holds row (l&15), k-chunk (l>>4)*8 (contiguous bf16x8)
    const int rA = lane & 15;
    const int kc = (lane >> 4) * 8;
    bf16x8 af[MR], wf[NF];
#pragma unroll
    for (int i = 0; i < MR; i++)
      af[i] = *(const bf16x8*)&tA[(wr * WR + i * 16 + rA) * 32 + kc];
#pragma unroll
    for (int j = 0; j < NF; j++)
      wf[j] = *(const bf16x8*)&tW[(wc * WC + j * 16 + rA) * 32 + kc];
#pragma unroll
    for (int i = 0; i < MR; i++)
#pragma unroll
      for (int j = 0; j < NF; j++)
        acc[i][j] = __builtin_amdgcn_mfma_f32_16x16x32_bf16(af[i], wf[j], acc[i][j], 0, 0, 0);
  }

  // C/D layout: col = lane&15, row = (lane>>4)*4 + reg  [m89-verified]
  const int cr = (lane >> 4) * 4;
  const int cc = lane & 15;
#pragma unroll
  for (int i = 0; i < MR; i++) {
#pragma unroll
    for (int j = 0; j < NF; j++) {
      const int row0 = bm + wr * WR + i * 16 + cr;
      const int col = bn + wc * WC + j * 16 + cc;
#pragma unroll
      for (int q = 0; q < 4; q++) {
        float v = acc[i][j][q];
        size_t idx = (size_t)(row0 + q) * N + col;
        if (OUT_BF16) {
          ((unsigned short*)OutV)[idx] = f2bf(v);
        } else {
          if (EPI) v = fmaf(U[idx], Dv[col], v);
          ((float*)OutV)[idx] = v;
        }
      }
    }
  }
}

// Phase A: local scan over CL steps from zero state. Bu16: [L][512] uints,
// each uint = packed bf16 (im<<16)|re for state p. fp32 recurrence.
__global__ __launch_bounds__(256) void scan_local(
    const unsigned int* __restrict__ Bu16, const float* __restrict__ prm,
    float4* __restrict__ finals) {
  int tid = blockIdx.x * 256 + threadIdx.x;
  int p = tid & (P_DIM - 1);
  int c = tid >> 9;
  float m00 = prm[0 * P_DIM + p], m01 = prm[1 * P_DIM + p];
  float m10 = prm[2 * P_DIM + p], m11 = prm[3 * P_DIM + p];
  float dts = prm[4 * P_DIM + p], dts2 = prm[5 * P_DIM + p];
  float x1r = 0.f, x2r = 0.f, x1i = 0.f, x2i = 0.f;
  const unsigned int* src = Bu16 + (size_t)c * CL * P_DIM + p;
#pragma unroll 8
  for (int i = 0; i < CL; i++) {
    unsigned int v = src[(size_t)i * P_DIM];
    float bx = bflo(v), by = bfhi(v);
    float n1r = fmaf(m00, x1r, fmaf(m01, x2r, dts * bx));
    float n2r = fmaf(m10, x1r, fmaf(m11, x2r, dts2 * bx));
    float n1i = fmaf(m00, x1i, fmaf(m01, x2i, dts * by));
    float n2i = fmaf(m10, x1i, fmaf(m11, x2i, dts2 * by));
    x1r = n1r; x2r = n2r; x1i = n1i; x2i = n2i;
  }
  finals[c * P_DIM + p] = make_float4(x1r, x2r, x1i, x2i);
}

// Phase B: Hillis-Steele log-scan over chunks; step matrix squares each round.
__global__ __launch_bounds__(NC) void scan_carry(
    const float4* __restrict__ finals, const float* __restrict__ prm,
    float4* __restrict__ carry) {
  int p = blockIdx.x;
  int c = threadIdx.x;
  __shared__ float4 sb[NC];
  float m00 = prm[6 * P_DIM + p], m01 = prm[7 * P_DIM + p];
  float m10 = prm[8 * P_DIM + p], m11 = prm[9 * P_DIM + p];
  float4 b = finals[c * P_DIM + p];
  for (int o = 1; o < NC; o <<= 1) {
    sb[c] = b;
    __syncthreads();
    float4 nb = (c >= o) ? sb[c - o] : make_float4(0.f, 0.f, 0.f, 0.f);
    __syncthreads();
    b.x = fmaf(m00, nb.x, fmaf(m01, nb.y, b.x));
    b.y = fmaf(m10, nb.x, fmaf(m11, nb.y, b.y));
    b.z = fmaf(m00, nb.z, fmaf(m01, nb.w, b.z));
    b.w = fmaf(m10, nb.z, fmaf(m11, nb.w, b.w));
    float n00 = m00 * m00 + m01 * m10;
    float n01 = m00 * m01 + m01 * m11;
    float n10 = m10 * m00 + m11 * m10;
    float n11 = m10 * m01 + m11 * m11;
    m00 = n00; m01 = n01; m10 = n10; m11 = n11;
  }
  if (c + 1 < NC) carry[(c + 1) * P_DIM + p] = b;
  if (c == 0) carry[p] = make_float4(0.f, 0.f, 0.f, 0.f);
}

// Phase C: redo local scan with carry-in; overwrite Bu16[t][p] with ys=x2 (bf16 pair).
// In-place safe: thread (c,p) reads then writes only its own elements.
__global__ __launch_bounds__(256) void scan_final(
    unsigned int* __restrict__ Bu16, const float* __restrict__ prm,
    const float4* __restrict__ carry) {
  int tid = blockIdx.x * 256 + threadIdx.x;
  int p = tid & (P_DIM - 1);
  int c = tid >> 9;
  float m00 = prm[0 * P_DIM + p], m01 = prm[1 * P_DIM + p];
  float m10 = prm[2 * P_DIM + p], m11 = prm[3 * P_DIM + p];
  float dts = prm[4 * P_DIM + p], dts2 = prm[5 * P_DIM + p];
  float4 s = carry[c * P_DIM + p];
  float x1r = s.x, x2r = s.y, x1i = s.z, x2i = s.w;
  unsigned int* src = Bu16 + (size_t)c * CL * P_DIM + p;
#pragma unroll 8
  for (int i = 0; i < CL; i++) {
    unsigned int v = src[(size_t)i * P_DIM];
    float bx = bflo(v), by = bfhi(v);
    float n1r = fmaf(m00, x1r, fmaf(m01, x2r, dts * bx));
    float n2r = fmaf(m10, x1r, fmaf(m11, x2r, dts2 * bx));
    float n1i = fmaf(m00, x1i, fmaf(m01, x2i, dts * by));
    float n2i = fmaf(m10, x1i, fmaf(m11, x2i, dts2 * by));
    src[(size_t)i * P_DIM] = (unsigned int)f2bf(n2r) | ((unsigned int)f2bf(n2i) << 16);
    x1r = n1r; x2r = n2r; x1i = n1i; x2i = n2i;
  }
}

extern "C" void kernel_launch(void* const* d_in, const int* in_sizes, int n_in,
                              void* d_out, int out_size, void* d_ws, size_t ws_size,
                              hipStream_t stream) {
  const float* u      = (const float*)d_in[0];  // (L, H)
  const float* A_diag = (const float*)d_in[1];
  const float* G_diag = (const float*)d_in[2];
  const float* dt     = (const float*)d_in[3];
  const float* B      = (const float*)d_in[4];  // (P, H, 2)
  const float* C      = (const float*)d_in[5];  // (H, P, 2)
  const float* D      = (const float*)d_in[6];  // (H,)
  float* out = (float*)d_out;

  // Workspace (bytes): Bu16 33.55MB | ub 8.39MB | W1b 0.5MB | W2b 0.5MB | prm | finals 2MB | carry 2MB  (~47MB)
  char* w = (char*)d_ws;
  unsigned short* Bu16 = (unsigned short*)w;                               // L*1024 bf16
  unsigned short* ub   = (unsigned short*)(w + (size_t)L_SEQ * 1024 * 2);  // L*256 bf16
  unsigned short* W1b  = ub + (size_t)L_SEQ * H_DIM;                       // 1024*256
  unsigned short* W2b  = W1b + 1024 * H_DIM;                               // 256*1024
  float* prm    = (float*)(W2b + H_DIM * 1024);                            // 10*512 (pad 8192)
  float* finals = prm + 8192;                                              // NC*P*4
  float* carryb = finals + (size_t)NC * P_DIM * 4;                         // NC*P*4

  // merged prep: params (2 blocks) + W1b (1024) + W2b (1024) + cast_u (4096)
  prep_all<<<2 + 1024 + 1024 + 4096, 256, 0, stream>>>(
      A_diag, G_diag, dt, B, C, u, prm, W1b, W2b, ub);

  // GEMM1: Bu16[L][1024] = ub[L][256] @ W1b^T  (bf16 out), 128x128 tile
  gemm_mfma<128, 128, true, false><<<dim3(L_SEQ / 128, 1024 / 128), 256, 0, stream>>>(
      ub, W1b, Bu16, L_SEQ, 1024, H_DIM, nullptr, nullptr);

  scan_local<<<(NC * P_DIM) / 256, 256, 0, stream>>>(
      (const unsigned int*)Bu16, prm, (float4*)finals);
  scan_carry<<<P_DIM, NC, 0, stream>>>(
      (const float4*)finals, prm, (float4*)carryb);
  scan_final<<<(NC * P_DIM) / 256, 256, 0, stream>>>(
      (unsigned int*)Bu16, prm, (const float4*)carryb);

  // GEMM2: out[L][256] = ys[L][1024] @ W2b^T + u*D
  // 32x256 tile, grid (512,1): ys read once, 2 blocks/CU
  gemm_mfma<32, 256, false, true><<<dim3(L_SEQ / 32, 1), 256, 0, stream>>>(
      Bu16, W2b, out, L_SEQ, H_DIM, 1024, u, D);
}

// Round 10
// 79.544 us; speedup vs baseline: 3.5512x; 1.0497x over previous
//
#include <hip/hip_runtime.h>
#include <math.h>

// Problem constants: L=16384, H=256, P=512.
#define L_SEQ 16384
#define H_DIM 256
#define P_DIM 512
#define CL 32                 // scan chunk length == GEMM2 row-tile
#define NC (L_SEQ / CL)       // 512 chunks

typedef __attribute__((ext_vector_type(8))) short bf16x8;   // MFMA A/B fragment (4 VGPR)
typedef __attribute__((ext_vector_type(4))) float f32x4;    // MFMA C/D fragment

static __device__ __forceinline__ unsigned short f2bf(float f) {
  unsigned int u = __builtin_bit_cast(unsigned int, f);
  u += 0x7FFFu + ((u >> 16) & 1u);
  return (unsigned short)(u >> 16);
}
static __device__ __forceinline__ float bflo(unsigned int v) {
  return __builtin_bit_cast(float, v << 16);
}
static __device__ __forceinline__ float bfhi(unsigned int v) {
  return __builtin_bit_cast(float, v & 0xFFFF0000u);
}
static __device__ __forceinline__ float bf2f(unsigned short s) {
  return __builtin_bit_cast(float, (unsigned int)s << 16);
}

// Merged prep (branch by blockIdx, wave-uniform):
//  [0,2): params; [2,1026): W1b; [1026,2050): W2b; [2050,6146): cast u->ub
__global__ __launch_bounds__(256) void prep_all(
    const float* __restrict__ A_diag, const float* __restrict__ G_diag,
    const float* __restrict__ dt, const float* __restrict__ B,
    const float* __restrict__ C, const float* __restrict__ u,
    float* __restrict__ prm, unsigned short* __restrict__ W1b,
    unsigned short* __restrict__ W2b, unsigned short* __restrict__ ub) {
  const int b = blockIdx.x;
  const int t = threadIdx.x;
  if (b < 2) {
    int p = b * 256 + t;
    float dts = 1.0f / (1.0f + expf(-dt[p]));
    float G = fmaxf(G_diag[p], 0.0f);
    float g = dts * G;
    float root = sqrtf(1.0f - g);
    float denom = fmaxf(dts * dts, 1e-6f);
    float A_low  = (2.0f - g - 2.0f * root) / denom;
    float A_high = (2.0f - g + 2.0f * root) / denom;
    float Ad = A_diag[p];
    float A = A_low + fmaxf(Ad - A_low, 0.0f) - fmaxf(Ad - A_high, 0.0f);
    float m00 = 1.0f - g;
    float m01 = -dts * A;
    float m10 = dts * (1.0f - g);
    float m11 = 1.0f - dts * dts * A;
    float c00 = m00, c01 = m01, c10 = m10, c11 = m11;
#pragma unroll
    for (int i = 0; i < 5; i++) {   // M^32 by squaring (CL=32); rho(M)<=1
      float n00 = c00 * c00 + c01 * c10;
      float n01 = c00 * c01 + c01 * c11;
      float n10 = c10 * c00 + c11 * c10;
      float n11 = c10 * c01 + c11 * c11;
      c00 = n00; c01 = n01; c10 = n10; c11 = n11;
    }
    prm[0 * P_DIM + p] = m00;
    prm[1 * P_DIM + p] = m01;
    prm[2 * P_DIM + p] = m10;
    prm[3 * P_DIM + p] = m11;
    prm[4 * P_DIM + p] = dts;
    prm[5 * P_DIM + p] = dts * dts;
    prm[6 * P_DIM + p] = c00;
    prm[7 * P_DIM + p] = c01;
    prm[8 * P_DIM + p] = c10;
    prm[9 * P_DIM + p] = c11;
  } else if (b < 2 + 1024) {
    int idx = (b - 2) * 256 + t;          // W1b[n][k], n=2p+c, k=h
    int n = idx >> 8;
    int k = idx & 255;
    int p = n >> 1, c = n & 1;
    W1b[idx] = f2bf(B[(p * H_DIM + k) * 2 + c]);
  } else if (b < 2 + 2048) {
    int idx = (b - 1026) * 256 + t;       // W2b[n][k], n=h, k=2p+c
    int h = idx >> 10;
    int k = idx & 1023;
    int p = k >> 1, c = k & 1;
    float v = C[(h * P_DIM + p) * 2 + c];
    W2b[idx] = f2bf(c ? -v : v);
  } else {
    int idx = (b - 2050) * 256 + t;       // cast u
    float4 v = ((const float4*)u)[idx];
    ushort4 o;
    o.x = f2bf(v.x); o.y = f2bf(v.y); o.z = f2bf(v.z); o.w = f2bf(v.w);
    ((ushort4*)ub)[idx] = o;
  }
}

// bf16 MFMA GEMM (m97 structure): BM x BN tile, 256 threads = 4 waves (2x2), BK=32.
// A[M][K] bf16 row-major, W[N][K] bf16 row-major (pre-transposed), fp32 acc, bf16 out.
template <int BM, int BN>
__global__ __launch_bounds__(256) void gemm_mfma(
    const unsigned short* __restrict__ A, const unsigned short* __restrict__ W,
    unsigned short* __restrict__ Out, int M, int N, int K) {
  constexpr int WR = BM / 2;
  constexpr int MR = WR / 16;
  constexpr int WC = BN / 2;
  constexpr int NF = WC / 16;
  __shared__ unsigned short tA[BM * 32];   // linear (gload_lds dest)
  __shared__ unsigned short tW[BN * 32];
  const int tid = threadIdx.x;
  const int lane = tid & 63;
  const int wid = tid >> 6;
  const int wr = wid >> 1;
  const int wc = wid & 1;
  const int bm = blockIdx.x * BM;
  const int bn = blockIdx.y * BN;

  f32x4 acc[MR][NF] = {};

  const int srow = lane >> 2;
  const int soff = (lane & 3) * 8;

  for (int k0 = 0; k0 < K; k0 += 32) {
    __syncthreads();
#pragma unroll
    for (int c = wid; c < BM / 16; c += 4) {
      const unsigned short* src = A + (size_t)(bm + c * 16 + srow) * K + k0 + soff;
      __builtin_amdgcn_global_load_lds(
          (const __attribute__((address_space(1))) void*)src,
          (__attribute__((address_space(3))) void*)(tA + c * 512), 16, 0, 0);
    }
#pragma unroll
    for (int c = wid; c < BN / 16; c += 4) {
      const unsigned short* src = W + (size_t)(bn + c * 16 + srow) * K + k0 + soff;
      __builtin_amdgcn_global_load_lds(
          (const __attribute__((address_space(1))) void*)src,
          (__attribute__((address_space(3))) void*)(tW + c * 512), 16, 0, 0);
    }
    __syncthreads();

    const int rA = lane & 15;
    const int kc = (lane >> 4) * 8;
    bf16x8 af[MR], wf[NF];
#pragma unroll
    for (int i = 0; i < MR; i++)
      af[i] = *(const bf16x8*)&tA[(wr * WR + i * 16 + rA) * 32 + kc];
#pragma unroll
    for (int j = 0; j < NF; j++)
      wf[j] = *(const bf16x8*)&tW[(wc * WC + j * 16 + rA) * 32 + kc];
#pragma unroll
    for (int i = 0; i < MR; i++)
#pragma unroll
      for (int j = 0; j < NF; j++)
        acc[i][j] = __builtin_amdgcn_mfma_f32_16x16x32_bf16(af[i], wf[j], acc[i][j], 0, 0, 0);
  }

  const int cr = (lane >> 4) * 4;
  const int cc = lane & 15;
#pragma unroll
  for (int i = 0; i < MR; i++)
#pragma unroll
    for (int j = 0; j < NF; j++) {
      const int row0 = bm + wr * WR + i * 16 + cr;
      const int col = bn + wc * WC + j * 16 + cc;
#pragma unroll
      for (int q = 0; q < 4; q++)
        Out[(size_t)(row0 + q) * N + col] = f2bf(acc[i][j][q]);
    }
}

// Phase A: local scan over CL=32 steps from zero state. Bu16: [L][512] packed bf16 pairs.
__global__ __launch_bounds__(256) void scan_local(
    const unsigned int* __restrict__ Bu16, const float* __restrict__ prm,
    float4* __restrict__ finals) {
  int tid = blockIdx.x * 256 + threadIdx.x;
  int p = tid & (P_DIM - 1);
  int c = tid >> 9;
  float m00 = prm[0 * P_DIM + p], m01 = prm[1 * P_DIM + p];
  float m10 = prm[2 * P_DIM + p], m11 = prm[3 * P_DIM + p];
  float dts = prm[4 * P_DIM + p], dts2 = prm[5 * P_DIM + p];
  float x1r = 0.f, x2r = 0.f, x1i = 0.f, x2i = 0.f;
  const unsigned int* src = Bu16 + (size_t)c * CL * P_DIM + p;
#pragma unroll 8
  for (int i = 0; i < CL; i++) {
    unsigned int v = src[(size_t)i * P_DIM];
    float bx = bflo(v), by = bfhi(v);
    float n1r = fmaf(m00, x1r, fmaf(m01, x2r, dts * bx));
    float n2r = fmaf(m10, x1r, fmaf(m11, x2r, dts2 * bx));
    float n1i = fmaf(m00, x1i, fmaf(m01, x2i, dts * by));
    float n2i = fmaf(m10, x1i, fmaf(m11, x2i, dts2 * by));
    x1r = n1r; x2r = n2r; x1i = n1i; x2i = n2i;
  }
  finals[c * P_DIM + p] = make_float4(x1r, x2r, x1i, x2i);
}

// Phase B: Hillis-Steele over NC=512 chunks, one block per p, 512 threads.
__global__ __launch_bounds__(NC) void scan_carry(
    const float4* __restrict__ finals, const float* __restrict__ prm,
    float4* __restrict__ carry) {
  int p = blockIdx.x;
  int c = threadIdx.x;
  __shared__ float4 sb[NC];
  float m00 = prm[6 * P_DIM + p], m01 = prm[7 * P_DIM + p];
  float m10 = prm[8 * P_DIM + p], m11 = prm[9 * P_DIM + p];
  float4 b = finals[c * P_DIM + p];
  for (int o = 1; o < NC; o <<= 1) {
    sb[c] = b;
    __syncthreads();
    float4 nb = (c >= o) ? sb[c - o] : make_float4(0.f, 0.f, 0.f, 0.f);
    __syncthreads();
    b.x = fmaf(m00, nb.x, fmaf(m01, nb.y, b.x));
    b.y = fmaf(m10, nb.x, fmaf(m11, nb.y, b.y));
    b.z = fmaf(m00, nb.z, fmaf(m01, nb.w, b.z));
    b.w = fmaf(m10, nb.z, fmaf(m11, nb.w, b.w));
    float n00 = m00 * m00 + m01 * m10;
    float n01 = m00 * m01 + m01 * m11;
    float n10 = m10 * m00 + m11 * m10;
    float n11 = m10 * m01 + m11 * m11;
    m00 = n00; m01 = n01; m10 = n10; m11 = n11;
  }
  if (c + 1 < NC) carry[(c + 1) * P_DIM + p] = b;
  if (c == 0) carry[p] = make_float4(0.f, 0.f, 0.f, 0.f);
}

// GEMM2 with fused scan_final: block = 32 rows (one CL chunk) x full N=256.
// Prologue: recompute ys for the 32 rows from Bu16 + carry (fp32 recurrence),
// deposit bf16 into XOR-swizzled LDS A-tile (T2: byte ^= (row&7)<<4).
// K-loop: A from LDS (no staging), W2b tile via global_load_lds (16KB/step).
// Epilogue: out = acc + ub*D (fp32 out).
__global__ __launch_bounds__(256) void gemm2_fused(
    const unsigned int* __restrict__ Bu16, const float* __restrict__ prm,
    const float4* __restrict__ carry, const unsigned short* __restrict__ W2b,
    const unsigned short* __restrict__ ub, const float* __restrict__ Dv,
    float* __restrict__ out) {
  __shared__ unsigned int yA[32 * 512];       // 64KB: ys[row][p] packed bf16 (re,im), swizzled
  __shared__ unsigned short tW[256 * 32];     // 16KB W2b K-tile (linear, gload_lds dest)
  const int tid = threadIdx.x;
  const int lane = tid & 63;
  const int wid = tid >> 6;
  const int row0 = blockIdx.x * 32;

  // ---- prologue: 2 p-columns per thread, 32-step recurrence
#pragma unroll
  for (int h = 0; h < 2; h++) {
    const int p = tid + h * 256;
    float m00 = prm[0 * P_DIM + p], m01 = prm[1 * P_DIM + p];
    float m10 = prm[2 * P_DIM + p], m11 = prm[3 * P_DIM + p];
    float dts = prm[4 * P_DIM + p], dts2 = prm[5 * P_DIM + p];
    float4 s = carry[(size_t)blockIdx.x * P_DIM + p];
    float x1r = s.x, x2r = s.y, x1i = s.z, x2i = s.w;
    const unsigned int* src = Bu16 + (size_t)row0 * P_DIM + p;
#pragma unroll 8
    for (int i = 0; i < 32; i++) {
      unsigned int v = src[(size_t)i * P_DIM];
      float bx = bflo(v), by = bfhi(v);
      float n1r = fmaf(m00, x1r, fmaf(m01, x2r, dts * bx));
      float n2r = fmaf(m10, x1r, fmaf(m11, x2r, dts2 * bx));
      float n1i = fmaf(m00, x1i, fmaf(m01, x2i, dts * by));
      float n2i = fmaf(m10, x1i, fmaf(m11, x2i, dts2 * by));
      // swizzled store: uint index (i*512+p) ^ ((i&7)<<2)  == byte ^ ((i&7)<<4)
      yA[(i * 512 + p) ^ ((i & 7) << 2)] =
          (unsigned int)f2bf(n2r) | ((unsigned int)f2bf(n2i) << 16);
      x1r = n1r; x2r = n2r; x1i = n1i; x2i = n2i;
    }
  }

  // ---- K-loop: 32 steps of BK=32 over K=1024
  const int srow = lane >> 2;
  const int soff = (lane & 3) * 8;
  const int wr = wid >> 1;          // row half (16 rows)
  const int wc = wid & 1;           // col half (128 cols)
  const int rA = lane & 15;
  const int kc = (lane >> 4) * 8;
  const int arow = wr * 16 + rA;
  const unsigned short* yAs = (const unsigned short*)yA;
  f32x4 acc[8] = {};

  for (int k0 = 0; k0 < 1024; k0 += 32) {
    __syncthreads();   // first iteration also fences prologue LDS writes
#pragma unroll
    for (int c = wid; c < 16; c += 4) {
      const unsigned short* src = W2b + (size_t)(c * 16 + srow) * 1024 + k0 + soff;
      __builtin_amdgcn_global_load_lds(
          (const __attribute__((address_space(1))) void*)src,
          (__attribute__((address_space(3))) void*)(tW + c * 512), 16, 0, 0);
    }
    __syncthreads();

    // A-frag from swizzled LDS: short index (arow*1024 + k) ^ ((arow&7)<<3)
    bf16x8 af = *(const bf16x8*)&yAs[((size_t)arow * 1024 + k0 + kc) ^ ((arow & 7) << 3)];
#pragma unroll
    for (int j = 0; j < 8; j++) {
      bf16x8 wf = *(const bf16x8*)&tW[(wc * 128 + j * 16 + rA) * 32 + kc];
      acc[j] = __builtin_amdgcn_mfma_f32_16x16x32_bf16(af, wf, acc[j], 0, 0, 0);
    }
  }

  // ---- epilogue: out = acc + ub*D  (C/D: col=lane&15, row=(lane>>4)*4+q)
  const int cr = (lane >> 4) * 4;
  const int cc = lane & 15;
#pragma unroll
  for (int j = 0; j < 8; j++) {
    const int col = wc * 128 + j * 16 + cc;
    const float d = Dv[col];
#pragma unroll
    for (int q = 0; q < 4; q++) {
      const int row = row0 + wr * 16 + cr + q;
      const size_t idx = (size_t)row * H_DIM + col;
      out[idx] = fmaf(bf2f(ub[idx]), d, acc[j][q]);
    }
  }
}

extern "C" void kernel_launch(void* const* d_in, const int* in_sizes, int n_in,
                              void* d_out, int out_size, void* d_ws, size_t ws_size,
                              hipStream_t stream) {
  const float* u      = (const float*)d_in[0];  // (L, H)
  const float* A_diag = (const float*)d_in[1];
  const float* G_diag = (const float*)d_in[2];
  const float* dt     = (const float*)d_in[3];
  const float* B      = (const float*)d_in[4];  // (P, H, 2)
  const float* C      = (const float*)d_in[5];  // (H, P, 2)
  const float* D      = (const float*)d_in[6];  // (H,)
  float* out = (float*)d_out;

  // Workspace: Bu16 33.55MB | ub 8.39MB | W1b 0.5MB | W2b 0.5MB | prm | finals 4MB | carry 4MB (~51MB)
  char* w = (char*)d_ws;
  unsigned short* Bu16 = (unsigned short*)w;                               // L*1024 bf16
  unsigned short* ub   = (unsigned short*)(w + (size_t)L_SEQ * 1024 * 2);  // L*256 bf16
  unsigned short* W1b  = ub + (size_t)L_SEQ * H_DIM;                       // 1024*256
  unsigned short* W2b  = W1b + 1024 * H_DIM;                               // 256*1024
  float* prm    = (float*)(W2b + H_DIM * 1024);                            // 10*512 (pad 8192)
  float* finals = prm + 8192;                                              // NC*P*4
  float* carryb = finals + (size_t)NC * P_DIM * 4;                         // NC*P*4

  prep_all<<<2 + 1024 + 1024 + 4096, 256, 0, stream>>>(
      A_diag, G_diag, dt, B, C, u, prm, W1b, W2b, ub);

  // GEMM1: Bu16[L][1024] = ub[L][256] @ W1b^T (bf16 out), 128x128 tile
  gemm_mfma<128, 128><<<dim3(L_SEQ / 128, 1024 / 128), 256, 0, stream>>>(
      ub, W1b, Bu16, L_SEQ, 1024, H_DIM);

  scan_local<<<(NC * P_DIM) / 256, 256, 0, stream>>>(
      (const unsigned int*)Bu16, prm, (float4*)finals);
  scan_carry<<<P_DIM, NC, 0, stream>>>(
      (const float4*)finals, prm, (float4*)carryb);

  // GEMM2 + fused scan_final: 512 blocks, one 32-row chunk each
  gemm2_fused<<<L_SEQ / 32, 256, 0, stream>>>(
      (const unsigned int*)Bu16, prm, (const float4*)carryb, W2b, ub, D, out);
}